// Round 3
// baseline (589.741 us; speedup 1.0000x reference)
//
#include <hip/hip_runtime.h>

#define LEAK 0.333f
#define BN_EPS 1e-4f

typedef __fp16 h2 __attribute__((ext_vector_type(2)));
typedef __fp16 h8 __attribute__((ext_vector_type(8)));
typedef float  f4 __attribute__((ext_vector_type(4)));

union H8 { h2 p[4]; h8 v; };

// ---------------------------------------------------------------------------
// fill: table[out_idx[i]*4 + kern_idx[i]] = i   (unique slots -> plain stores)
// ---------------------------------------------------------------------------
__global__ __launch_bounds__(256) void fill_table_kernel(
    const int* __restrict__ out_idx, const int* __restrict__ kern_idx,
    int* __restrict__ table, int n_in)
{
    const int i = blockIdx.x * 256 + threadIdx.x;
    if (i < n_in) {
        table[out_idx[i] * 4 + kern_idx[i]] = i;
    }
}

// ---------------------------------------------------------------------------
// convert: feat f32 -> fp16 once (sequential stream), same cvt_pkrtz pairing
// as the MFMA A-fragment build used before -> bit-identical conv inputs.
// Shrinks the randomly-gathered working set 192 MB -> 96 MB (fits the 256 MB
// Infinity Cache), and halves gather instructions in both conv passes.
// ---------------------------------------------------------------------------
__global__ __launch_bounds__(256) void convert_kernel(
    const f4* __restrict__ in, H8* __restrict__ out16, int n8)
{
    int i = blockIdx.x * 256 + threadIdx.x;
    const int stride = gridDim.x * 256;
    for (; i < n8; i += stride) {
        f4 a = in[2 * i];
        f4 b = in[2 * i + 1];
        H8 o;
        o.p[0] = __builtin_amdgcn_cvt_pkrtz(a.x, a.y);
        o.p[1] = __builtin_amdgcn_cvt_pkrtz(a.z, a.w);
        o.p[2] = __builtin_amdgcn_cvt_pkrtz(b.x, b.y);
        o.p[3] = __builtin_amdgcn_cvt_pkrtz(b.z, b.w);
        out16[i] = o;
    }
}

// ---------------------------------------------------------------------------
// MFMA gather conv, two passes sharing one body:
//   APPLY=false : conv -> BN statistics only (no output write)
//   APPLY=true  : conv recomputed (bit-identical) -> y=scale*acc+shift,
//                 LeakyReLU, single store of the final result
//
// one wave per 16-output-row tile; 16x16x32 f16 MFMA, N=64 via 4 n-tiles
//   A frag: lane holds row (lane&15), k-slice (lane>>4)*8..+7  (per slot)
//           = one 16-B fp16 load per slot from feat16
//   B frag: lane holds col (lane&15)+n*16, same k enumeration
//   C/D   : col = lane&15, row = (lane>>4)*4 + reg   [HW-verified layout]
// Gather is branchless: invalid slots read a 64-B zero row (cndmask on the
// address, no divergent exec-mask dance). Pipeline: table prefetched 3 tiles
// ahead, feature rows 2 tiles ahead (fp16 halves the in-flight VGPR cost).
// ---------------------------------------------------------------------------
template <bool APPLY>
__global__ __launch_bounds__(256, 2) void conv_pass_kernel(
    const __fp16* __restrict__ f16, const float* __restrict__ weight,
    const int4* __restrict__ table, const __fp16* __restrict__ zrow,
    float* __restrict__ out, float* __restrict__ stats, int n_out)
{
    const int lane = threadIdx.x & 63;
    const int wv   = threadIdx.x >> 6;
    const int c    = lane & 15;   // A row within tile / B,C col within n-tile
    const int g    = lane >> 4;   // k-group (and C row group)
    const int g8   = g * 8;

    // ---- B fragments: bw[slot][ntile] = W[slot][k = g8..g8+7][col = n*16+c]
    H8 bw[4][4];
#pragma unroll
    for (int s = 0; s < 4; ++s)
#pragma unroll
        for (int n = 0; n < 4; ++n)
#pragma unroll
            for (int e = 0; e < 4; ++e) {
                const int k0 = g8 + 2 * e;
                bw[s][n].p[e] = __builtin_amdgcn_cvt_pkrtz(
                    weight[(s * 32 + k0    ) * 64 + n * 16 + c],
                    weight[(s * 32 + k0 + 1) * 64 + n * 16 + c]);
            }

    // ---- BN affine params (apply pass only); channel = n*16 + c
    float scl[4], sft[4];
    if (APPLY) {
#pragma unroll
        for (int n = 0; n < 4; ++n) {
            scl[n] = stats[128 + n * 16 + c];
            sft[n] = stats[192 + n * 16 + c];
        }
    }

    float sv[4] = {0.f, 0.f, 0.f, 0.f};
    float qv[4] = {0.f, 0.f, 0.f, 0.f};

    const int ntiles  = (n_out + 15) >> 4;
    const int ts      = gridDim.x * 4;
    const int t0      = blockIdx.x * 4 + wv;

    // table fetch for tile x (lane c -> row x*16+c), -1 when out of range
    auto loadtab = [&](int x) -> int4 {
        int4 r = make_int4(-1, -1, -1, -1);
        if (x < ntiles) {
            const int row = x * 16 + c;
            if (row < n_out) r = table[row];
        }
        return r;
    };
    // branchless slot gather: invalid -> 16 B from the shared zero row
    auto ld = [&](int si) -> h8 {
        const __fp16* p = (si >= 0) ? (f16 + ((size_t)si * 32 + g8))
                                    : (zrow + g8);
        return *(const h8*)p;
    };

    int4 tb2 = loadtab(t0 + 2 * ts);
    int4 tbA = loadtab(t0);
    int4 tbB = loadtab(t0 + ts);

    h8 fA[4], fB[4];
    fA[0] = ld(tbA.x); fA[1] = ld(tbA.y); fA[2] = ld(tbA.z); fA[3] = ld(tbA.w);
    fB[0] = ld(tbB.x); fB[1] = ld(tbB.y); fB[2] = ld(tbB.z); fB[3] = ld(tbB.w);

    for (int t = t0; t < ntiles; t += ts) {
        // ---- prefetch: table 3 ahead, features 2 ahead
        int4 tb3 = loadtab(t + 3 * ts);
        h8 fC[4];
        fC[0] = ld(tb2.x); fC[1] = ld(tb2.y); fC[2] = ld(tb2.z); fC[3] = ld(tb2.w);

        // ---- 16 MFMAs: 4 K-steps (slots) x 4 N-tiles on the oldest buffer
        f4 acc[4];
#pragma unroll
        for (int n = 0; n < 4; ++n) acc[n] = 0.f;
#pragma unroll
        for (int s = 0; s < 4; ++s)
#pragma unroll
            for (int n = 0; n < 4; ++n)
                acc[n] = __builtin_amdgcn_mfma_f32_16x16x32_f16(
                    fA[s], bw[s][n].v, acc[n], 0, 0, 0);

        // ---- stats or fused BN+LeakyReLU store
        const int rbase = t * 16 + g * 4;
#pragma unroll
        for (int r = 0; r < 4; ++r) {
            const int ro = rbase + r;
            if (APPLY) {
                if (ro < n_out) {
                    float* po = out + (size_t)ro * 64 + c;
#pragma unroll
                    for (int n = 0; n < 4; ++n) {
                        float y = fmaf(acc[n][r], scl[n], sft[n]);
                        po[n * 16] = y > 0.f ? y : LEAK * y;
                    }
                }
            } else {
#pragma unroll
                for (int n = 0; n < 4; ++n) {   // OOB rows contribute exact 0
                    sv[n] += acc[n][r];
                    qv[n] = fmaf(acc[n][r], acc[n][r], qv[n]);
                }
            }
        }

        // ---- rotate pipeline registers (static indices only)
#pragma unroll
        for (int s = 0; s < 4; ++s) { fA[s] = fB[s]; fB[s] = fC[s]; }
        tb2 = tb3;
    }

    if constexpr (!APPLY) {
        // ---- column sums: fold the 4 k-groups (lanes c, c+16, c+32, c+48)
#pragma unroll
        for (int n = 0; n < 4; ++n) {
            sv[n] += __shfl_xor(sv[n], 16);
            sv[n] += __shfl_xor(sv[n], 32);
            qv[n] += __shfl_xor(qv[n], 16);
            qv[n] += __shfl_xor(qv[n], 32);
        }

        __shared__ float ls[4][64];
        __shared__ float lq[4][64];
        if (lane < 16) {
#pragma unroll
            for (int n = 0; n < 4; ++n) {
                ls[wv][n * 16 + lane] = sv[n];
                lq[wv][n * 16 + lane] = qv[n];
            }
        }
        __syncthreads();
        if (wv == 0) {
            float ts2 = ls[0][lane] + ls[1][lane] + ls[2][lane] + ls[3][lane];
            float tq2 = lq[0][lane] + lq[1][lane] + lq[2][lane] + lq[3][lane];
            atomicAdd(&stats[lane], ts2);
            atomicAdd(&stats[64 + lane], tq2);
        }
    }
}

// ---------------------------------------------------------------------------
__global__ void finalize_kernel(float* __restrict__ stats,
                                const float* __restrict__ gamma,
                                const float* __restrict__ beta, float inv_n)
{
    const int j = threadIdx.x;  // 64 threads
    float mean = stats[j] * inv_n;
    float var  = fmaf(-mean, mean, stats[64 + j] * inv_n);
    var = fmaxf(var, 0.f);
    float scale = gamma[j] * rsqrtf(var + BN_EPS);
    stats[128 + j] = scale;
    stats[192 + j] = beta[j] - mean * scale;
}

// ---------------------------------------------------------------------------
extern "C" void kernel_launch(void* const* d_in, const int* in_sizes, int n_in,
                              void* d_out, int out_size, void* d_ws, size_t ws_size,
                              hipStream_t stream)
{
    // Inputs: 0=features 1=weight 2=bias(cancels in BN) 3=gamma 4=beta
    //         5=out_idx 6=kern_idx 7=n_out(scalar, unused: out_size/64)
    const float* feat     = (const float*)d_in[0];
    const float* weight   = (const float*)d_in[1];
    const float* gamma    = (const float*)d_in[3];
    const float* beta     = (const float*)d_in[4];
    const int*   out_idx  = (const int*)d_in[5];
    const int*   kern_idx = (const int*)d_in[6];
    const int n_active = in_sizes[5];
    const int n_out    = out_size / 64;
    float* out   = (float*)d_out;

    // workspace layout:
    //   [0,1024)            stats: sums / sumsqs / scale / shift
    //   [1024,1088)         zero row (64 B) for invalid gather slots
    //   [2048, +n_out*16)   table (int4 per output row)
    //   [aligned, +96 MB)   feat16
    float*  stats = (float*)d_ws;
    __fp16* zrow  = (__fp16*)((char*)d_ws + 1024);
    int*    table = (int*)((char*)d_ws + 2048);
    size_t  f16_off = 2048 + (((size_t)n_out * 16 + 255) & ~(size_t)255);
    __fp16* f16   = (__fp16*)((char*)d_ws + f16_off);

    (void)hipMemsetAsync(d_ws, 0, 1088, stream);   // stats sums + zero row
    (void)hipMemsetAsync(table, 0xFF, (size_t)n_out * 4 * sizeof(int), stream);

    fill_table_kernel<<<(n_active + 255) / 256, 256, 0, stream>>>(
        out_idx, kern_idx, table, n_active);
    convert_kernel<<<2048, 256, 0, stream>>>(
        (const f4*)feat, (H8*)f16, n_active * 4);
    conv_pass_kernel<false><<<2048, 256, 0, stream>>>(
        f16, weight, (const int4*)table, zrow, nullptr, stats, n_out);
    finalize_kernel<<<1, 64, 0, stream>>>(stats, gamma, beta, 1.0f / (float)n_out);
    conv_pass_kernel<true><<<2048, 256, 0, stream>>>(
        f16, weight, (const int4*)table, zrow, out, stats, n_out);
}